// Round 3
// baseline (219.110 us; speedup 1.0000x reference)
//
#include <hip/hip_runtime.h>
#include <stdint.h>

#define NCLS    80
#define NA_TOT  8400     // 6400 + 1600 + 400
#define NBATCH  32
#define MAXDET  300
#define SSORT   2048
#define CONFTHR 0.001f

// ---------------------------------------------------------------------------
// Bit-exact reconstruction of XLA:CPU f32 exp (Eigen/Cephes pexp, no FMA) and
// logistic = 1/(1+exp(-x)). Validated absmax==0.0 rounds 1-2. DO NOT TOUCH.
// ---------------------------------------------------------------------------
__device__ __forceinline__ float xla_expf(float in) {
  const float exp_hi = 88.3762626647950f;
  const float exp_lo = -88.3762626647949f;
  const float LOG2EF = 1.44269504088896341f;
  const float C1 = 0.693359375f;
  const float C2 = -2.12194440e-4f;
  const float p0 = 1.9875691500E-4f, p1 = 1.3981999507E-3f, p2 = 8.3334519073E-3f;
  const float p3 = 4.1665795894E-2f, p4 = 1.6666665459E-1f, p5 = 5.0000001201E-1f;
  float x = fminf(fmaxf(in, exp_lo), exp_hi);
  float fx = floorf(__fadd_rn(__fmul_rn(x, LOG2EF), 0.5f));
  float tmp = __fmul_rn(C1, fx);
  float z   = __fmul_rn(C2, fx);
  x = __fsub_rn(x, tmp);
  x = __fsub_rn(x, z);
  float y = __fadd_rn(__fmul_rn(x, p0), p1);
  y = __fadd_rn(__fmul_rn(y, x), p2);
  y = __fadd_rn(__fmul_rn(y, x), p3);
  y = __fadd_rn(__fmul_rn(y, x), p4);
  y = __fadd_rn(__fmul_rn(y, x), p5);
  y = __fadd_rn(__fmul_rn(y, __fmul_rn(x, x)), x);
  y = __fadd_rn(1.0f, y);
  int m = (int)fx;
  float s = __uint_as_float((uint32_t)(m + 127) << 23);
  float r = __fmul_rn(y, s);
  return fmaxf(r, in);
}

__device__ __forceinline__ float xla_sigmoid(float v) {
  float e = xla_expf(-v);
  float den = __fadd_rn(1.0f, e);
  return 1.0f / den;
}

// ---------------------------------------------------------------------------
// Kernel 1: DFL decode + class max/argmax, per (batch, anchor).
// cls: top-2 logit tracking + single sigmoid fast path; exact 80-sigmoid
// slow path when (best-second) < 1e-4 or best > 5.0 (sigmoid-monotonicity
// margin vs <=2-ulp Cephes wobble: DeltaS >= S'(5)*1e-4 = 6.6e-7 >> 2.4e-7).
// ---------------------------------------------------------------------------
__global__ __launch_bounds__(128) void yolo_decode_kernel(
    const float* __restrict__ f0, const float* __restrict__ f1,
    const float* __restrict__ f2,
    float4* __restrict__ oboxes, float* __restrict__ oconf,
    float* __restrict__ oclsf) {
  int t = blockIdx.x * 128 + threadIdx.x;
  if (t >= NBATCH * NA_TOT) return;
  int b = t / NA_TOT;
  int a = t - b * NA_TOT;

  const float* base; int ai, W; float stridef;
  if (a < 6400)      { base = f0 + (size_t)b * (144 * 6400); ai = a;        W = 80; stridef = 8.0f;  }
  else if (a < 8000) { base = f1 + (size_t)b * (144 * 1600); ai = a - 6400; W = 40; stridef = 16.0f; }
  else               { base = f2 + (size_t)b * (144 * 400);  ai = a - 8000; W = 20; stridef = 32.0f; }
  int Alvl = W * W;
  const float* cptr = base + ai;
  float ax = __fadd_rn((float)(ai % W), 0.5f);
  float ay = __fadd_rn((float)(ai / W), 0.5f);

  // ---- DFL box (bit-exact, unchanged from validated r1) ----
  float ltrb[4];
  #pragma unroll
  for (int fs = 0; fs < 4; ++fs) {
    float d[16];
    float mx = -INFINITY;
    #pragma unroll
    for (int r = 0; r < 16; ++r) {
      d[r] = cptr[(size_t)(fs * 16 + r) * Alvl];
      mx = fmaxf(mx, d[r]);
    }
    float e[16];
    float ssum = 0.0f;
    #pragma unroll
    for (int r = 0; r < 16; ++r) {
      e[r] = xla_expf(__fsub_rn(d[r], mx));
      ssum = __fadd_rn(ssum, e[r]);
    }
    float acc = 0.0f;
    #pragma unroll
    for (int r = 0; r < 16; ++r) {
      float p = e[r] / ssum;
      acc = __fadd_rn(acc, __fmul_rn(p, (float)r));
    }
    ltrb[fs] = acc;
  }

  float x1 = __fsub_rn(ax, ltrb[0]);
  float y1 = __fsub_rn(ay, ltrb[1]);
  float x2 = __fadd_rn(ax, ltrb[2]);
  float y2 = __fadd_rn(ay, ltrb[3]);
  float cx = __fmul_rn(__fadd_rn(x1, x2), 0.5f);
  float cy = __fmul_rn(__fadd_rn(y1, y2), 0.5f);
  float w  = __fsub_rn(x2, x1);
  float h  = __fsub_rn(y2, y1);
  float4 box = make_float4(__fmul_rn(cx, stridef), __fmul_rn(cy, stridef),
                           __fmul_rn(w, stridef),  __fmul_rn(h, stridef));

  // ---- class: top-2 logit scan ----
  float best = -INFINITY, second = -INFINITY;
  int bi = 0;
  #pragma unroll 8
  for (int k = 0; k < NCLS; ++k) {
    float v = cptr[(size_t)(64 + k) * Alvl];
    if (v > best)        { second = best; best = v; bi = k; }
    else if (v > second) { second = v; }
  }
  float conf;
  if (__fsub_rn(best, second) < 1e-4f || best > 5.0f) {
    // exact slow path: identical to validated r1 semantics
    float bs = -INFINITY; int bj = 0;
    for (int k = 0; k < NCLS; ++k) {
      float v = cptr[(size_t)(64 + k) * Alvl];
      float s = xla_sigmoid(v);
      if (s > bs) { bs = s; bj = k; }
    }
    conf = bs; bi = bj;
  } else {
    conf = xla_sigmoid(best);
  }
  conf = (conf > CONFTHR) ? conf : 0.0f;

  oboxes[t] = box;
  oconf[t]  = conf;
  oclsf[t]  = (float)bi;
}

// ---------------------------------------------------------------------------
// Kernel 2: per-image adaptive radix select + rank-by-count + bit-row NMS.
// ---------------------------------------------------------------------------
struct LdsA {                         // selection phase (~66.4 KB)
  unsigned confL[NA_TOT];             // 33600 B
  unsigned hist[2048];                //  8192 B
  unsigned Tarr[2049];                //  8196 B
  unsigned long long sortkeys[SSORT]; // 16384 B
};
struct LdsB {                         // NMS phase (160832 B total)
  unsigned long long rows[1024][16];  // 131072 B (overlaps all of LdsA)
  float    rowdata[1024][6];          //  24576 B (disjoint from LdsA)
  unsigned list[1024];                //   4096 B (disjoint)
  unsigned clsCnt[NCLS];              //    320 B
  unsigned clsBase[NCLS];             //    320 B
  unsigned clsCur[NCLS];              //    320 B
  unsigned long long alive[16];       //    128 B
};

__global__ __launch_bounds__(1024) void yolo_selectnms_kernel(
    const float4* __restrict__ boxes, const float* __restrict__ conf,
    const float* __restrict__ clsf, float* __restrict__ out) {
  __shared__ union { LdsA a; LdsB b; } u;
  __shared__ unsigned s_need, s_prefix, s_found, s_B, s_scnt, s_cut, s_done,
                      s_efinal;
  int b   = blockIdx.x;
  int tid = threadIdx.x;
  const unsigned* confu = (const unsigned*)conf + (size_t)b * NA_TOT;

  // ---- P0: stage conf bits; zero NMS-phase state living outside LdsA ----
  for (int i = tid; i < NA_TOT; i += 1024) u.a.confL[i] = confu[i];
  #pragma unroll
  for (int q = 0; q < 6; ++q) u.b.rowdata[tid][q] = 0.0f;
  if (tid < NCLS) u.b.clsCnt[tid] = 0;
  if (tid < 16)   u.b.alive[tid]  = 0ull;
  if (tid == 0) { s_need = 1024; s_prefix = 0; s_cut = 0; s_done = 0;
                  s_scnt = 0; s_efinal = 0; }
  __syncthreads();

  // ---- P1: adaptive radix descent (11+11+10 bits, exit when <= SSORT) ----
  for (int lv = 0; lv < 3; ++lv) {
    __syncthreads();
    if (s_done) break;                     // uniform (read after barrier)
    for (int i = tid; i < 2048; i += 1024) u.a.hist[i] = 0;
    if (tid == 0) { s_found = 0; s_B = 0; }
    __syncthreads();
    unsigned pfx = s_prefix;
    for (int i = tid; i < NA_TOT; i += 1024) {
      unsigned c = u.a.confL[i];
      if (c == 0) continue;
      bool in; unsigned bin;
      if (lv == 0)      { in = true;               bin = c >> 21; }
      else if (lv == 1) { in = ((c >> 21) == pfx); bin = (c >> 10) & 0x7FF; }
      else              { in = ((c >> 10) == pfx); bin = c & 0x3FF; }
      if (in) atomicAdd(&u.a.hist[bin], 1u);
    }
    __syncthreads();
    if (tid < 64) {                        // wave-0 suffix scan (validated r2)
      unsigned carry = 0;
      if (tid == 0) u.a.Tarr[2048] = 0;
      for (int ch = 31; ch >= 0; --ch) {
        int bb = ch * 64 + tid;
        unsigned v = u.a.hist[bb];
        #pragma unroll
        for (int off = 1; off < 64; off <<= 1) {
          unsigned t2 = __shfl_down(v, off);
          if (tid + off < 64) v += t2;
        }
        u.a.Tarr[bb] = v + carry;
        carry += __shfl(v, 0);
      }
    }
    __syncthreads();
    unsigned need = s_need;
    for (int i = tid; i < 2048; i += 1024) {
      unsigned h = u.a.hist[i];
      if (h > 0 && u.a.Tarr[i + 1] < need && u.a.Tarr[i + 1] + h >= need) {
        s_B = (unsigned)i; s_found = 1;    // unique writer (T monotone)
      }
    }
    __syncthreads();
    if (tid == 0) {
      if (!s_found) {                      // total positives < need (lv0 only)
        s_cut = 1; s_done = 1;             // select all nonzero
      } else {
        unsigned B = s_B;
        unsigned selcnt = u.a.Tarr[B];     // count >= lower edge of bin B
        bool fin = (selcnt <= (unsigned)SSORT) || (lv == 2);
        if (fin) {
          s_done = 1;
          if (lv == 0)      s_cut = B << 21;
          else if (lv == 1) s_cut = (s_prefix << 21) | (B << 10);
          else              s_cut = (s_prefix << 10) | B;
        } else {
          s_need = s_need - u.a.Tarr[B + 1];
          s_prefix = (lv == 0) ? B : ((s_prefix << 11) | B);
        }
      }
    }
  }
  __syncthreads();

  // ---- P2: compact selected (c >= cut, c != 0), unordered ----
  unsigned cut = s_cut;
  for (int i = tid; i < NA_TOT; i += 1024) {
    unsigned c = u.a.confL[i];
    if (c != 0 && c >= cut) {
      unsigned p = atomicAdd(&s_scnt, 1u);
      if (p < SSORT)
        u.a.sortkeys[p] = ((unsigned long long)c << 32) |
                          (unsigned long long)(0xFFFFFFFFu - (unsigned)i);
    }
  }
  __syncthreads();

  // ---- P3: rank-by-count (barrier-free; LDS broadcast) + scatter ----
  unsigned scnt = s_scnt; if (scnt > SSORT) scnt = SSORT;
  for (unsigned e = tid; e < scnt; e += 1024) {
    unsigned long long mykey = u.a.sortkeys[e];
    unsigned r = 0;
    #pragma unroll 4
    for (unsigned j = 0; j < scnt; ++j)
      r += (u.a.sortkeys[j] > mykey) ? 1u : 0u;
    if (r < 1024) {                        // == lax.top_k truncation @ NCAND
      unsigned a = 0xFFFFFFFFu - (unsigned)(mykey & 0xFFFFFFFFull);
      float4 cb = boxes[(size_t)b * NA_TOT + a];
      float cls = clsf[(size_t)b * NA_TOT + a];
      u.b.rowdata[r][0] = cb.x;
      u.b.rowdata[r][1] = cb.y;
      u.b.rowdata[r][2] = cb.z;
      u.b.rowdata[r][3] = cb.w;
      u.b.rowdata[r][4] = __uint_as_float((unsigned)(mykey >> 32));
      u.b.rowdata[r][5] = cls;
      atomicOr(&u.b.alive[r >> 6], 1ull << (r & 63));
      atomicAdd(&u.b.clsCnt[(int)cls], 1u);
    }
  }
  __syncthreads();      // sortkeys dead; rows region reusable

  // ---- P4: zero suppression rows; class bases ----
  #pragma unroll
  for (int q = 0; q < 16; ++q) u.b.rows[tid][q] = 0ull;
  if (tid == 0) {
    unsigned acc = 0;
    for (int c2 = 0; c2 < NCLS; ++c2) {
      u.b.clsBase[c2] = acc; u.b.clsCur[c2] = acc; acc += u.b.clsCnt[c2];
    }
  }
  __syncthreads();

  // ---- P5: per-class candidate lists (thread tid = rank tid) ----
  bool valid = (u.b.alive[tid >> 6] >> (tid & 63)) & 1ull;
  float mycls = u.b.rowdata[tid][5];
  if (valid) {
    unsigned p = atomicAdd(&u.b.clsCur[(int)mycls], 1u);
    u.b.list[p] = (unsigned)tid;
  }
  __syncthreads();

  // ---- P6: suppression-bit rows (same-class pairs only) ----
  if (valid) {
    float bx0 = u.b.rowdata[tid][0], by0 = u.b.rowdata[tid][1];
    float bw0 = u.b.rowdata[tid][2], bh0 = u.b.rowdata[tid][3];
    int c = (int)mycls;
    unsigned base = u.b.clsBase[c], cnt = u.b.clsCnt[c];
    float off = __fmul_rn(mycls, 7680.0f);
    float hw  = __fmul_rn(bw0, 0.5f), hh = __fmul_rn(bh0, 0.5f);
    float wx1 = __fadd_rn(__fsub_rn(bx0, hw), off);
    float wy1 = __fadd_rn(__fsub_rn(by0, hh), off);
    float wx2 = __fadd_rn(__fadd_rn(bx0, hw), off);
    float wy2 = __fadd_rn(__fadd_rn(by0, hh), off);
    float a1  = __fmul_rn(__fsub_rn(wx2, wx1), __fsub_rn(wy2, wy1));
    for (unsigned l = 0; l < cnt; ++l) {
      int j = (int)u.b.list[base + l];
      float jx = u.b.rowdata[j][0], jy = u.b.rowdata[j][1];
      float jw = u.b.rowdata[j][2], jh = u.b.rowdata[j][3];
      float jhw = __fmul_rn(jw, 0.5f), jhh = __fmul_rn(jh, 0.5f);
      float jx1 = __fadd_rn(__fsub_rn(jx, jhw), off);
      float jy1 = __fadd_rn(__fsub_rn(jy, jhh), off);
      float jx2 = __fadd_rn(__fadd_rn(jx, jhw), off);
      float jy2 = __fadd_rn(__fadd_rn(jy, jhh), off);
      float ltx = fmaxf(wx1, jx1), lty = fmaxf(wy1, jy1);
      float rbx = fminf(wx2, jx2), rby = fminf(wy2, jy2);
      float iw = fmaxf(__fsub_rn(rbx, ltx), 0.0f);
      float ih = fmaxf(__fsub_rn(rby, lty), 0.0f);
      float inter = __fmul_rn(iw, ih);
      float a2 = __fmul_rn(__fsub_rn(jx2, jx1), __fsub_rn(jy2, jy1));
      float den = __fadd_rn(__fsub_rn(__fadd_rn(a1, a2), inter), 1e-7f);
      float iou = inter / den;
      if (iou > 0.7f)
        u.b.rows[tid][j >> 6] |= (1ull << (j & 63));
    }
  }
  __syncthreads();

  // ---- P7: single-wave greedy walk (barrier-free; ffs over alive mask) ----
  float* orow = out + (size_t)b * (MAXDET * 6);
  if (tid < 64) {
    int lane = tid;
    unsigned long long am = (lane < 16) ? u.b.alive[lane] : 0ull;
    int e = 0;
    while (e < MAXDET) {
      unsigned long long bal = __ballot(am != 0ull);
      if (bal == 0ull) break;
      int f    = __ffsll((unsigned long long)bal) - 1;
      int myb  = __ffsll((unsigned long long)am) - 1;
      int bitp = __shfl(myb, f);
      int r    = f * 64 + bitp;                     // winner rank
      if (lane < 6) orow[e * 6 + lane] = u.b.rowdata[r][lane];
      unsigned long long rowv = (lane < 16) ? u.b.rows[r][lane] : 0ull;
      am &= ~rowv;      // winner self-suppresses (self-IoU ~ 1), as reference
      ++e;
    }
    if (tid == 0) s_efinal = (unsigned)e;
  }
  __syncthreads();

  // ---- P8: zero-fill remaining output rows (replaces host memset) ----
  for (int i = (int)s_efinal * 6 + tid; i < MAXDET * 6; i += 1024)
    orow[i] = 0.0f;
}

extern "C" void kernel_launch(void* const* d_in, const int* in_sizes, int n_in,
                              void* d_out, int out_size, void* d_ws, size_t ws_size,
                              hipStream_t stream) {
  const float* f0 = (const float*)d_in[0];
  const float* f1 = (const float*)d_in[1];
  const float* f2 = (const float*)d_in[2];
  float* out = (float*)d_out;

  char* ws = (char*)d_ws;
  float4* boxes = (float4*)ws;                                   // 32*8400*16 B
  float*  conf  = (float*)(ws + (size_t)NBATCH * NA_TOT * 16);   // 32*8400*4 B
  float*  clsf  = (float*)(ws + (size_t)NBATCH * NA_TOT * 20);   // 32*8400*4 B

  int tot = NBATCH * NA_TOT;
  yolo_decode_kernel<<<(tot + 127) / 128, 128, 0, stream>>>(f0, f1, f2,
                                                            boxes, conf, clsf);
  yolo_selectnms_kernel<<<NBATCH, 1024, 0, stream>>>(boxes, conf, clsf, out);
}

// Round 4
// 168.157 us; speedup vs baseline: 1.3030x; 1.3030x over previous
//
#include <hip/hip_runtime.h>
#include <stdint.h>

#define NCLS    80
#define NA_TOT  8400     // 6400 + 1600 + 400
#define NBATCH  32
#define MAXDET  300
#define SSORT   2048
#define CONFTHR 0.001f
#define TILES_PER_IMG 132   // 100 + 25 + 7

// ---------------------------------------------------------------------------
// Bit-exact reconstruction of XLA:CPU f32 exp (Eigen/Cephes pexp, no FMA) and
// logistic = 1/(1+exp(-x)). Validated absmax==0.0 rounds 1-3. DO NOT TOUCH.
// ---------------------------------------------------------------------------
__device__ __forceinline__ float xla_expf(float in) {
  const float exp_hi = 88.3762626647950f;
  const float exp_lo = -88.3762626647949f;
  const float LOG2EF = 1.44269504088896341f;
  const float C1 = 0.693359375f;
  const float C2 = -2.12194440e-4f;
  const float p0 = 1.9875691500E-4f, p1 = 1.3981999507E-3f, p2 = 8.3334519073E-3f;
  const float p3 = 4.1665795894E-2f, p4 = 1.6666665459E-1f, p5 = 5.0000001201E-1f;
  float x = fminf(fmaxf(in, exp_lo), exp_hi);
  float fx = floorf(__fadd_rn(__fmul_rn(x, LOG2EF), 0.5f));
  float tmp = __fmul_rn(C1, fx);
  float z   = __fmul_rn(C2, fx);
  x = __fsub_rn(x, tmp);
  x = __fsub_rn(x, z);
  float y = __fadd_rn(__fmul_rn(x, p0), p1);
  y = __fadd_rn(__fmul_rn(y, x), p2);
  y = __fadd_rn(__fmul_rn(y, x), p3);
  y = __fadd_rn(__fmul_rn(y, x), p4);
  y = __fadd_rn(__fmul_rn(y, x), p5);
  y = __fadd_rn(__fmul_rn(y, __fmul_rn(x, x)), x);
  y = __fadd_rn(1.0f, y);
  int m = (int)fx;
  float s = __uint_as_float((uint32_t)(m + 127) << 23);
  float r = __fmul_rn(y, s);
  return fmaxf(r, in);
}

__device__ __forceinline__ float xla_sigmoid(float v) {
  float e = xla_expf(-v);
  float den = __fadd_rn(1.0f, e);
  return 1.0f / den;
}

// ---------------------------------------------------------------------------
// Kernel 1: tiled decode. Block = 256 threads = 64 anchors x 4 workers.
// Stage [144][64] tile into LDS (pad 65), then per-anchor arithmetic is
// bit-identical to the validated per-thread version.
// ---------------------------------------------------------------------------
__global__ __launch_bounds__(256) void yolo_decode_kernel(
    const float* __restrict__ f0, const float* __restrict__ f1,
    const float* __restrict__ f2,
    float4* __restrict__ oboxes, float* __restrict__ oconf,
    float* __restrict__ oclsf) {
  __shared__ float sm[144 * 65];                  // 37,440 B
  int bx  = blockIdx.x;
  int b   = bx / TILES_PER_IMG;
  int r   = bx - b * TILES_PER_IMG;
  int tid = threadIdx.x;

  const float* base; int a0, W, NV, aG0; float stridef;
  if (r < 100)      { base = f0 + (size_t)b * (144 * 6400); W = 80; a0 = r * 64;
                      NV = 64; stridef = 8.0f;  aG0 = a0; }
  else if (r < 125) { base = f1 + (size_t)b * (144 * 1600); W = 40; a0 = (r - 100) * 64;
                      NV = 64; stridef = 16.0f; aG0 = 6400 + a0; }
  else              { base = f2 + (size_t)b * (144 * 400);  W = 20; a0 = (r - 125) * 64;
                      NV = (a0 + 64 <= 400) ? 64 : (400 - a0); stridef = 32.0f;
                      aG0 = 8000 + a0; }
  int Alvl = W * W;

  // ---- stage: 144 rows x NV floats, float4 chunks, high MLP ----
  int nch4   = NV >> 2;                 // 16 or 4 float4 per row
  int chunks = 144 * nch4;
  for (int c = tid; c < chunks; c += 256) {
    int row = c / nch4;
    int c4  = c - row * nch4;
    float4 v = *reinterpret_cast<const float4*>(base + (size_t)row * Alvl + a0 + c4 * 4);
    float* dst = &sm[row * 65 + c4 * 4];
    dst[0] = v.x; dst[1] = v.y; dst[2] = v.z; dst[3] = v.w;
  }
  __syncthreads();

  int idx = tid >> 2;                   // anchor in tile
  int w   = tid & 3;                    // worker (DFL side / class slice)
  if (idx >= NV) return;                // whole trailing waves exit (NV=16 tile)
  int ai = a0 + idx;
  float ax = __fadd_rn((float)(ai % W), 0.5f);
  float ay = __fadd_rn((float)(ai / W), 0.5f);

  // ---- DFL side w (bit-exact r1 sequence, source = LDS) ----
  float d[16];
  float mx = -INFINITY;
  #pragma unroll
  for (int rr = 0; rr < 16; ++rr) {
    d[rr] = sm[(w * 16 + rr) * 65 + idx];
    mx = fmaxf(mx, d[rr]);
  }
  float e[16]; float ssum = 0.0f;
  #pragma unroll
  for (int rr = 0; rr < 16; ++rr) {
    e[rr] = xla_expf(__fsub_rn(d[rr], mx));
    ssum = __fadd_rn(ssum, e[rr]);
  }
  float acc = 0.0f;
  #pragma unroll
  for (int rr = 0; rr < 16; ++rr) {
    float p = e[rr] / ssum;
    acc = __fadd_rn(acc, __fmul_rn(p, (float)rr));
  }

  int l0 = (tid & 63) & ~3;             // lane of worker 0 for this anchor
  float lt0 = __shfl(acc, l0 + 0);
  float lt1 = __shfl(acc, l0 + 1);
  float lt2 = __shfl(acc, l0 + 2);
  float lt3 = __shfl(acc, l0 + 3);

  // ---- class top-2, 20 classes per worker (ascending k, strict >) ----
  float best = -INFINITY, second = -INFINITY; int bi = 0;
  #pragma unroll 5
  for (int k = 0; k < 20; ++k) {
    float v = sm[(64 + w * 20 + k) * 65 + idx];
    if (v > best)        { second = best; best = v; bi = w * 20 + k; }
    else if (v > second) { second = v; }
  }
  // merge 4 workers: lower worker wins ties == global first-max semantics
  float gb = __shfl(best, l0 + 0), gs = __shfl(second, l0 + 0);
  int   gi = __shfl(bi,   l0 + 0);
  #pragma unroll
  for (int q = 1; q < 4; ++q) {
    float bq = __shfl(best, l0 + q), sq = __shfl(second, l0 + q);
    int   iq = __shfl(bi,   l0 + q);
    if (bq > gb) { gs = fmaxf(gb, sq); gb = bq; gi = iq; }
    else         { gs = fmaxf(gs, bq); }
  }

  float conf = 0.0f; int cls = gi;
  if (__fsub_rn(gb, gs) < 1e-4f || gb > 5.0f) {
    // exact slow path (rare): identical to validated r1 80-sigmoid scan
    if (w == 0) {
      float bs = -INFINITY; int bj = 0;
      for (int k = 0; k < NCLS; ++k) {
        float v = sm[(64 + k) * 65 + idx];
        float s = xla_sigmoid(v);
        if (s > bs) { bs = s; bj = k; }
      }
      conf = bs; cls = bj;
    }
  } else {
    conf = xla_sigmoid(gb);
  }

  if (w == 0) {
    float x1 = __fsub_rn(ax, lt0);
    float y1 = __fsub_rn(ay, lt1);
    float x2 = __fadd_rn(ax, lt2);
    float y2 = __fadd_rn(ay, lt3);
    float cx = __fmul_rn(__fadd_rn(x1, x2), 0.5f);
    float cy = __fmul_rn(__fadd_rn(y1, y2), 0.5f);
    float ww = __fsub_rn(x2, x1);
    float hh = __fsub_rn(y2, y1);
    int t = b * NA_TOT + aG0 + idx;
    oboxes[t] = make_float4(__fmul_rn(cx, stridef), __fmul_rn(cy, stridef),
                            __fmul_rn(ww, stridef), __fmul_rn(hh, stridef));
    conf = (conf > CONFTHR) ? conf : 0.0f;
    oconf[t] = conf;
    oclsf[t] = (float)cls;
  }
}

// ---------------------------------------------------------------------------
// Kernel 2: per-image exact radix select (per-wave hists) + rank-by-count
//           + bit-row NMS (validated r2/r3 structure).
// ---------------------------------------------------------------------------
struct LdsA {                           // selection phase (~68.5 KB)
  unsigned confL[NA_TOT];               // 33600 B
  unsigned hist[16][257];               // 16448 B (padded: wave-parallel banks)
  unsigned tot[257];                    //  1028 B
  unsigned Tarr[257];                   //  1028 B
  unsigned long long sortkeys[SSORT];   // 16384 B
};
struct LdsB {                           // NMS phase (160832 B)
  unsigned long long rows[1024][16];    // 131072 B (overlaps LdsA)
  float    rowdata[1024][6];            //  24576 B (disjoint from LdsA)
  unsigned list[1024];                  //   4096 B (disjoint)
  unsigned clsCnt[NCLS];
  unsigned clsBase[NCLS];
  unsigned clsCur[NCLS];
  unsigned long long alive[16];
};

__global__ __launch_bounds__(1024) void yolo_selectnms_kernel(
    const float4* __restrict__ boxes, const float* __restrict__ conf,
    const float* __restrict__ clsf, float* __restrict__ out) {
  __shared__ union { LdsA a; LdsB b; } u;
  __shared__ unsigned s_need, s_prefix, s_found, s_B, s_scnt, s_cut, s_done,
                      s_efinal;
  int b    = blockIdx.x;
  int tid  = threadIdx.x;
  int lane = tid & 63;
  int wv   = tid >> 6;
  const unsigned* confu = (const unsigned*)conf + (size_t)b * NA_TOT;

  // ---- P0: stage conf bits; zero NMS-phase state outside LdsA ----
  for (int i = tid; i < NA_TOT; i += 1024) u.a.confL[i] = confu[i];
  #pragma unroll
  for (int q = 0; q < 6; ++q) u.b.rowdata[tid][q] = 0.0f;
  if (tid < NCLS) u.b.clsCnt[tid] = 0;
  if (tid < 16)   u.b.alive[tid]  = 0ull;
  if (tid == 0) { s_need = 1024; s_prefix = 0; s_cut = 0; s_done = 0;
                  s_scnt = 0; s_efinal = 0; }
  __syncthreads();

  // ---- P1: exact 4-level 8-bit radix descent (per-wave histograms) ----
  for (int lv = 0; lv < 4; ++lv) {
    __syncthreads();
    if (s_done) break;                          // uniform
    for (int i = tid; i < 16 * 257; i += 1024) ((unsigned*)u.a.hist)[i] = 0;
    if (tid == 0) { s_found = 0; s_B = 0; }
    __syncthreads();
    unsigned pfx = s_prefix;
    for (int it = 0; it < 9; ++it) {
      int i = tid + it * 1024;
      if (i < NA_TOT) {
        unsigned c = u.a.confL[i];
        if (c != 0) {
          bool in; unsigned bin;
          if (lv == 0)      { in = true;                bin = c >> 23; }
          else if (lv == 1) { in = ((c >> 23) == pfx);  bin = (c >> 15) & 0xFF; }
          else if (lv == 2) { in = ((c >> 15) == pfx);  bin = (c >> 7) & 0xFF; }
          else              { in = ((c >> 7)  == pfx);  bin = c & 0x7F; }
          if (in) atomicAdd(&u.a.hist[wv][bin], 1u);
        }
      }
    }
    __syncthreads();
    if (tid < 256) {                            // reduce 16 wave-hists
      unsigned s = 0;
      #pragma unroll
      for (int q = 0; q < 16; ++q) s += u.a.hist[q][tid];
      u.a.tot[tid] = s;
    }
    __syncthreads();
    if (tid < 64) {                             // suffix scan, 4 chunks of 64
      unsigned carry = 0;
      if (tid == 0) u.a.Tarr[256] = 0;
      for (int ch = 3; ch >= 0; --ch) {
        int bb = ch * 64 + tid;
        unsigned v = u.a.tot[bb];
        #pragma unroll
        for (int off = 1; off < 64; off <<= 1) {
          unsigned t2 = __shfl_down(v, off);
          if (tid + off < 64) v += t2;
        }
        u.a.Tarr[bb] = v + carry;
        carry += __shfl(v, 0);
      }
    }
    __syncthreads();
    unsigned need = s_need;
    if (tid < 256) {
      unsigned h = u.a.tot[tid];
      if (h > 0 && u.a.Tarr[tid + 1] < need && u.a.Tarr[tid + 1] + h >= need) {
        s_B = (unsigned)tid; s_found = 1;       // unique writer (T monotone)
      }
    }
    __syncthreads();
    if (tid == 0) {
      if (!s_found) { s_cut = 1; s_done = 1; }  // <1024 nonzero total (lv0)
      else {
        unsigned B = s_B;
        if (lv == 3) { s_cut = (s_prefix << 7) | B; s_done = 1; }
        else { s_need = need - u.a.Tarr[B + 1]; s_prefix = (s_prefix << 8) | B; }
      }
    }
  }
  __syncthreads();

  // ---- P2: compact (ballot-aggregated; 1 atomic per wave per pass) ----
  unsigned cut = s_cut;
  for (int it = 0; it < 9; ++it) {
    int i = tid + it * 1024;
    unsigned c = (i < NA_TOT) ? u.a.confL[i] : 0u;
    bool sel = (c != 0 && c >= cut);
    unsigned long long bal = __ballot(sel);
    unsigned base2 = 0;
    if (lane == 0 && bal) base2 = atomicAdd(&s_scnt, (unsigned)__popcll(bal));
    base2 = __shfl(base2, 0);
    if (sel) {
      unsigned p = base2 + (unsigned)__popcll(bal & ((1ull << lane) - 1ull));
      if (p < SSORT)
        u.a.sortkeys[p] = ((unsigned long long)c << 32) |
                          (unsigned long long)(0xFFFFFFFFu - (unsigned)i);
    }
  }
  __syncthreads();

  // ---- P3: rank-by-count (LDS broadcast) + scatter to rank slots ----
  unsigned scnt = s_scnt; if (scnt > SSORT) scnt = SSORT;
  for (unsigned e = tid; e < scnt; e += 1024) {
    unsigned long long mykey = u.a.sortkeys[e];
    unsigned r = 0;
    #pragma unroll 4
    for (unsigned j = 0; j < scnt; ++j)
      r += (u.a.sortkeys[j] > mykey) ? 1u : 0u;
    if (r < 1024) {                             // == lax.top_k truncation
      unsigned a = 0xFFFFFFFFu - (unsigned)(mykey & 0xFFFFFFFFull);
      float4 cb = boxes[(size_t)b * NA_TOT + a];
      float cls = clsf[(size_t)b * NA_TOT + a];
      u.b.rowdata[r][0] = cb.x;
      u.b.rowdata[r][1] = cb.y;
      u.b.rowdata[r][2] = cb.z;
      u.b.rowdata[r][3] = cb.w;
      u.b.rowdata[r][4] = __uint_as_float((unsigned)(mykey >> 32));
      u.b.rowdata[r][5] = cls;
      atomicOr(&u.b.alive[r >> 6], 1ull << (r & 63));
      atomicAdd(&u.b.clsCnt[(int)cls], 1u);
    }
  }
  __syncthreads();      // sortkeys dead; rows region reusable

  // ---- P4: zero suppression rows; class bases ----
  #pragma unroll
  for (int q = 0; q < 16; ++q) u.b.rows[tid][q] = 0ull;
  if (tid == 0) {
    unsigned acc = 0;
    for (int c2 = 0; c2 < NCLS; ++c2) {
      u.b.clsBase[c2] = acc; u.b.clsCur[c2] = acc; acc += u.b.clsCnt[c2];
    }
  }
  __syncthreads();

  // ---- P5: per-class candidate lists ----
  bool valid = (u.b.alive[tid >> 6] >> (tid & 63)) & 1ull;
  float mycls = u.b.rowdata[tid][5];
  if (valid) {
    unsigned p = atomicAdd(&u.b.clsCur[(int)mycls], 1u);
    u.b.list[p] = (unsigned)tid;
  }
  __syncthreads();

  // ---- P6: suppression-bit rows (same-class pairs only) ----
  if (valid) {
    float bx0 = u.b.rowdata[tid][0], by0 = u.b.rowdata[tid][1];
    float bw0 = u.b.rowdata[tid][2], bh0 = u.b.rowdata[tid][3];
    int c = (int)mycls;
    unsigned base = u.b.clsBase[c], cnt = u.b.clsCnt[c];
    float off = __fmul_rn(mycls, 7680.0f);
    float hw  = __fmul_rn(bw0, 0.5f), hh = __fmul_rn(bh0, 0.5f);
    float wx1 = __fadd_rn(__fsub_rn(bx0, hw), off);
    float wy1 = __fadd_rn(__fsub_rn(by0, hh), off);
    float wx2 = __fadd_rn(__fadd_rn(bx0, hw), off);
    float wy2 = __fadd_rn(__fadd_rn(by0, hh), off);
    float a1  = __fmul_rn(__fsub_rn(wx2, wx1), __fsub_rn(wy2, wy1));
    for (unsigned l = 0; l < cnt; ++l) {
      int j = (int)u.b.list[base + l];
      float jx = u.b.rowdata[j][0], jy = u.b.rowdata[j][1];
      float jw = u.b.rowdata[j][2], jh = u.b.rowdata[j][3];
      float jhw = __fmul_rn(jw, 0.5f), jhh = __fmul_rn(jh, 0.5f);
      float jx1 = __fadd_rn(__fsub_rn(jx, jhw), off);
      float jy1 = __fadd_rn(__fsub_rn(jy, jhh), off);
      float jx2 = __fadd_rn(__fadd_rn(jx, jhw), off);
      float jy2 = __fadd_rn(__fadd_rn(jy, jhh), off);
      float ltx = fmaxf(wx1, jx1), lty = fmaxf(wy1, jy1);
      float rbx = fminf(wx2, jx2), rby = fminf(wy2, jy2);
      float iw = fmaxf(__fsub_rn(rbx, ltx), 0.0f);
      float ih = fmaxf(__fsub_rn(rby, lty), 0.0f);
      float inter = __fmul_rn(iw, ih);
      float a2 = __fmul_rn(__fsub_rn(jx2, jx1), __fsub_rn(jy2, jy1));
      float den = __fadd_rn(__fsub_rn(__fadd_rn(a1, a2), inter), 1e-7f);
      float iou = inter / den;
      if (iou > 0.7f)
        u.b.rows[tid][j >> 6] |= (1ull << (j & 63));
    }
  }
  __syncthreads();

  // ---- P7: single-wave greedy walk ----
  float* orow = out + (size_t)b * (MAXDET * 6);
  if (tid < 64) {
    unsigned long long am = (lane < 16) ? u.b.alive[lane] : 0ull;
    int e = 0;
    while (e < MAXDET) {
      unsigned long long bal = __ballot(am != 0ull);
      if (bal == 0ull) break;
      int f    = __ffsll((unsigned long long)bal) - 1;
      int myb  = __ffsll((unsigned long long)am) - 1;
      int bitp = __shfl(myb, f);
      int r    = f * 64 + bitp;
      if (lane < 6) orow[e * 6 + lane] = u.b.rowdata[r][lane];
      unsigned long long rowv = (lane < 16) ? u.b.rows[r][lane] : 0ull;
      am &= ~rowv;
      ++e;
    }
    if (tid == 0) s_efinal = (unsigned)e;
  }
  __syncthreads();

  // ---- P8: zero-fill remaining output rows ----
  for (int i = (int)s_efinal * 6 + tid; i < MAXDET * 6; i += 1024)
    orow[i] = 0.0f;
}

extern "C" void kernel_launch(void* const* d_in, const int* in_sizes, int n_in,
                              void* d_out, int out_size, void* d_ws, size_t ws_size,
                              hipStream_t stream) {
  const float* f0 = (const float*)d_in[0];
  const float* f1 = (const float*)d_in[1];
  const float* f2 = (const float*)d_in[2];
  float* out = (float*)d_out;

  char* ws = (char*)d_ws;
  float4* boxes = (float4*)ws;                                   // 32*8400*16 B
  float*  conf  = (float*)(ws + (size_t)NBATCH * NA_TOT * 16);   // 32*8400*4 B
  float*  clsf  = (float*)(ws + (size_t)NBATCH * NA_TOT * 20);   // 32*8400*4 B

  yolo_decode_kernel<<<NBATCH * TILES_PER_IMG, 256, 0, stream>>>(
      f0, f1, f2, boxes, conf, clsf);
  yolo_selectnms_kernel<<<NBATCH, 1024, 0, stream>>>(boxes, conf, clsf, out);
}

// Round 5
// 162.525 us; speedup vs baseline: 1.3482x; 1.0347x over previous
//
#include <hip/hip_runtime.h>
#include <stdint.h>

#define NCLS    80
#define NA_TOT  8400     // 6400 + 1600 + 400
#define NBATCH  32
#define MAXDET  300
#define SSORT   2048
#define RANKCAP 1536
#define CONFTHR 0.001f
#define TILES_PER_IMG 132   // 100 + 25 + 7

// ---------------------------------------------------------------------------
// Bit-exact reconstruction of XLA:CPU f32 exp (Eigen/Cephes pexp, no FMA) and
// logistic = 1/(1+exp(-x)). Validated absmax==0.0 rounds 1-4. DO NOT TOUCH.
// ---------------------------------------------------------------------------
__device__ __forceinline__ float xla_expf(float in) {
  const float exp_hi = 88.3762626647950f;
  const float exp_lo = -88.3762626647949f;
  const float LOG2EF = 1.44269504088896341f;
  const float C1 = 0.693359375f;
  const float C2 = -2.12194440e-4f;
  const float p0 = 1.9875691500E-4f, p1 = 1.3981999507E-3f, p2 = 8.3334519073E-3f;
  const float p3 = 4.1665795894E-2f, p4 = 1.6666665459E-1f, p5 = 5.0000001201E-1f;
  float x = fminf(fmaxf(in, exp_lo), exp_hi);
  float fx = floorf(__fadd_rn(__fmul_rn(x, LOG2EF), 0.5f));
  float tmp = __fmul_rn(C1, fx);
  float z   = __fmul_rn(C2, fx);
  x = __fsub_rn(x, tmp);
  x = __fsub_rn(x, z);
  float y = __fadd_rn(__fmul_rn(x, p0), p1);
  y = __fadd_rn(__fmul_rn(y, x), p2);
  y = __fadd_rn(__fmul_rn(y, x), p3);
  y = __fadd_rn(__fmul_rn(y, x), p4);
  y = __fadd_rn(__fmul_rn(y, x), p5);
  y = __fadd_rn(__fmul_rn(y, __fmul_rn(x, x)), x);
  y = __fadd_rn(1.0f, y);
  int m = (int)fx;
  float s = __uint_as_float((uint32_t)(m + 127) << 23);
  float r = __fmul_rn(y, s);
  return fmaxf(r, in);
}

__device__ __forceinline__ float xla_sigmoid(float v) {
  float e = xla_expf(-v);
  float den = __fadd_rn(1.0f, e);
  return 1.0f / den;
}

// ---------------------------------------------------------------------------
// Kernel 1: tiled decode (validated r4, unchanged).
// ---------------------------------------------------------------------------
__global__ __launch_bounds__(256) void yolo_decode_kernel(
    const float* __restrict__ f0, const float* __restrict__ f1,
    const float* __restrict__ f2,
    float4* __restrict__ oboxes, float* __restrict__ oconf,
    float* __restrict__ oclsf) {
  __shared__ float sm[144 * 65];                  // 37,440 B
  int bx  = blockIdx.x;
  int b   = bx / TILES_PER_IMG;
  int r   = bx - b * TILES_PER_IMG;
  int tid = threadIdx.x;

  const float* base; int a0, W, NV, aG0; float stridef;
  if (r < 100)      { base = f0 + (size_t)b * (144 * 6400); W = 80; a0 = r * 64;
                      NV = 64; stridef = 8.0f;  aG0 = a0; }
  else if (r < 125) { base = f1 + (size_t)b * (144 * 1600); W = 40; a0 = (r - 100) * 64;
                      NV = 64; stridef = 16.0f; aG0 = 6400 + a0; }
  else              { base = f2 + (size_t)b * (144 * 400);  W = 20; a0 = (r - 125) * 64;
                      NV = (a0 + 64 <= 400) ? 64 : (400 - a0); stridef = 32.0f;
                      aG0 = 8000 + a0; }
  int Alvl = W * W;

  int nch4   = NV >> 2;
  int chunks = 144 * nch4;
  for (int c = tid; c < chunks; c += 256) {
    int row = c / nch4;
    int c4  = c - row * nch4;
    float4 v = *reinterpret_cast<const float4*>(base + (size_t)row * Alvl + a0 + c4 * 4);
    float* dst = &sm[row * 65 + c4 * 4];
    dst[0] = v.x; dst[1] = v.y; dst[2] = v.z; dst[3] = v.w;
  }
  __syncthreads();

  int idx = tid >> 2;
  int w   = tid & 3;
  if (idx >= NV) return;
  int ai = a0 + idx;
  float ax = __fadd_rn((float)(ai % W), 0.5f);
  float ay = __fadd_rn((float)(ai / W), 0.5f);

  float d[16];
  float mx = -INFINITY;
  #pragma unroll
  for (int rr = 0; rr < 16; ++rr) {
    d[rr] = sm[(w * 16 + rr) * 65 + idx];
    mx = fmaxf(mx, d[rr]);
  }
  float e[16]; float ssum = 0.0f;
  #pragma unroll
  for (int rr = 0; rr < 16; ++rr) {
    e[rr] = xla_expf(__fsub_rn(d[rr], mx));
    ssum = __fadd_rn(ssum, e[rr]);
  }
  float acc = 0.0f;
  #pragma unroll
  for (int rr = 0; rr < 16; ++rr) {
    float p = e[rr] / ssum;
    acc = __fadd_rn(acc, __fmul_rn(p, (float)rr));
  }

  int l0 = (tid & 63) & ~3;
  float lt0 = __shfl(acc, l0 + 0);
  float lt1 = __shfl(acc, l0 + 1);
  float lt2 = __shfl(acc, l0 + 2);
  float lt3 = __shfl(acc, l0 + 3);

  float best = -INFINITY, second = -INFINITY; int bi = 0;
  #pragma unroll 5
  for (int k = 0; k < 20; ++k) {
    float v = sm[(64 + w * 20 + k) * 65 + idx];
    if (v > best)        { second = best; best = v; bi = w * 20 + k; }
    else if (v > second) { second = v; }
  }
  float gb = __shfl(best, l0 + 0), gs = __shfl(second, l0 + 0);
  int   gi = __shfl(bi,   l0 + 0);
  #pragma unroll
  for (int q = 1; q < 4; ++q) {
    float bq = __shfl(best, l0 + q), sq = __shfl(second, l0 + q);
    int   iq = __shfl(bi,   l0 + q);
    if (bq > gb) { gs = fmaxf(gb, sq); gb = bq; gi = iq; }
    else         { gs = fmaxf(gs, bq); }
  }

  float conf = 0.0f; int cls = gi;
  if (__fsub_rn(gb, gs) < 1e-4f || gb > 5.0f) {
    if (w == 0) {
      float bs = -INFINITY; int bj = 0;
      for (int k = 0; k < NCLS; ++k) {
        float v = sm[(64 + k) * 65 + idx];
        float s = xla_sigmoid(v);
        if (s > bs) { bs = s; bj = k; }
      }
      conf = bs; cls = bj;
    }
  } else {
    conf = xla_sigmoid(gb);
  }

  if (w == 0) {
    float x1 = __fsub_rn(ax, lt0);
    float y1 = __fsub_rn(ay, lt1);
    float x2 = __fadd_rn(ax, lt2);
    float y2 = __fadd_rn(ay, lt3);
    float cx = __fmul_rn(__fadd_rn(x1, x2), 0.5f);
    float cy = __fmul_rn(__fadd_rn(y1, y2), 0.5f);
    float ww = __fsub_rn(x2, x1);
    float hh = __fsub_rn(y2, y1);
    int t = b * NA_TOT + aG0 + idx;
    oboxes[t] = make_float4(__fmul_rn(cx, stridef), __fmul_rn(cy, stridef),
                            __fmul_rn(ww, stridef), __fmul_rn(hh, stridef));
    conf = (conf > CONFTHR) ? conf : 0.0f;
    oconf[t] = conf;
    oclsf[t] = (float)cls;
  }
}

// ---------------------------------------------------------------------------
// Kernel 2: per-image exact top-1024 select + rank. Writes rowdata[1024][8],
// alive masks, class counts to global ws for the NMS kernel.
// ---------------------------------------------------------------------------
struct __align__(16) K2Lds {
  unsigned long long sortkeys[SSORT];   // 16384 B (offset 0: 16B-aligned)
  unsigned confL[NA_TOT];               // 33600 B
  unsigned hist[16][257];               // 16448 B (per-wave, padded)
  unsigned tot[257];
  unsigned Tarr[257];
  unsigned long long alive[16];
  unsigned clsCnt[NCLS];
};                                      // ~69 KB

__global__ __launch_bounds__(1024) void yolo_select_kernel(
    const float4* __restrict__ boxes, const float* __restrict__ conf,
    const float* __restrict__ clsf,
    float* __restrict__ g_rowd, unsigned long long* __restrict__ g_alive,
    unsigned* __restrict__ g_clsc) {
  __shared__ K2Lds u;
  __shared__ unsigned s_need, s_prefix, s_found, s_B, s_scnt, s_cut, s_done;
  int b    = blockIdx.x;
  int tid  = threadIdx.x;
  int lane = tid & 63;
  int wv   = tid >> 6;
  const unsigned* confu = (const unsigned*)conf + (size_t)b * NA_TOT;

  // ---- P0: stage conf bits; zero outputs ----
  for (int i = tid; i < NA_TOT; i += 1024) u.confL[i] = confu[i];
  {
    float4 z4 = make_float4(0.f, 0.f, 0.f, 0.f);
    float4* gr = (float4*)(g_rowd + (size_t)b * 1024 * 8);
    for (int k = tid; k < 2048; k += 1024) gr[k] = z4;   // 1024 rows x 32 B
  }
  if (tid < NCLS) u.clsCnt[tid] = 0;
  if (tid < 16)   u.alive[tid]  = 0ull;
  if (tid == 0) { s_need = 1024; s_prefix = 0; s_cut = 0; s_done = 0; s_scnt = 0; }
  __syncthreads();

  // ---- P1: adaptive 8-bit radix descent (exact selcnt bound) ----
  for (int lv = 0; lv < 4; ++lv) {
    __syncthreads();
    if (s_done) break;                          // uniform
    for (int i = tid; i < 16 * 257; i += 1024) ((unsigned*)u.hist)[i] = 0;
    if (tid == 0) { s_found = 0; s_B = 0; }
    __syncthreads();
    unsigned pfx = s_prefix;
    for (int it = 0; it < 9; ++it) {
      int i = tid + it * 1024;
      unsigned c = (i < NA_TOT) ? u.confL[i] : 0u;
      bool in; unsigned bin;
      if (lv == 0)      { in = true;                bin = c >> 23; }
      else if (lv == 1) { in = ((c >> 23) == pfx);  bin = (c >> 15) & 0xFF; }
      else if (lv == 2) { in = ((c >> 15) == pfx);  bin = (c >> 7) & 0xFF; }
      else              { in = ((c >> 7)  == pfx);  bin = c & 0x7F; }
      bool act = (c != 0) && in;
      unsigned long long ab = __ballot(act);
      if (ab) {                                 // wave-uniform branch
        int fl = __ffsll(ab) - 1;
        unsigned fbin = __shfl(bin, fl);
        unsigned long long same = __ballot(act && (bin == fbin));
        if (same == ab) {                       // all active lanes same bin
          if (lane == fl) atomicAdd(&u.hist[wv][fbin], (unsigned)__popcll(ab));
        } else if (act) {
          atomicAdd(&u.hist[wv][bin], 1u);
        }
      }
    }
    __syncthreads();
    if (tid < 256) {                            // reduce 16 wave-hists
      unsigned s = 0;
      #pragma unroll
      for (int q = 0; q < 16; ++q) s += u.hist[q][tid];
      u.tot[tid] = s;
    }
    __syncthreads();
    if (tid < 64) {                             // suffix scan (4 chunks of 64)
      unsigned carry = 0;
      if (tid == 0) u.Tarr[256] = 0;
      for (int ch = 3; ch >= 0; --ch) {
        int bb = ch * 64 + tid;
        unsigned v = u.tot[bb];
        #pragma unroll
        for (int off = 1; off < 64; off <<= 1) {
          unsigned t2 = __shfl_down(v, off);
          if (tid + off < 64) v += t2;
        }
        u.Tarr[bb] = v + carry;
        carry += __shfl(v, 0);
      }
    }
    __syncthreads();
    unsigned need = s_need;
    if (tid < 256) {
      unsigned h = u.tot[tid];
      if (h > 0 && u.Tarr[tid + 1] < need && u.Tarr[tid + 1] + h >= need) {
        s_B = (unsigned)tid; s_found = 1;       // unique writer (T monotone)
      }
    }
    __syncthreads();
    if (tid == 0) {
      if (!s_found) { s_cut = 1; s_done = 1; }  // <1024 nonzero total (lv0)
      else {
        unsigned B = s_B;
        unsigned selcnt = (1024u - need) + u.Tarr[B];  // exact: committed + >=binB
        if (selcnt <= (unsigned)RANKCAP || lv == 3) {
          s_done = 1;
          if (lv == 0)      s_cut = B << 23;
          else if (lv == 1) s_cut = (s_prefix << 23) | (B << 15);
          else if (lv == 2) s_cut = (s_prefix << 15) | (B << 7);
          else              s_cut = (s_prefix << 7)  | B;
        } else {
          s_need   = need - u.Tarr[B + 1];
          s_prefix = (s_prefix << 8) | B;
        }
      }
    }
  }
  __syncthreads();

  // ---- P2: ballot-aggregated compact ----
  unsigned cut = s_cut;
  for (int it = 0; it < 9; ++it) {
    int i = tid + it * 1024;
    unsigned c = (i < NA_TOT) ? u.confL[i] : 0u;
    bool sel = (c != 0 && c >= cut);
    unsigned long long bal = __ballot(sel);
    unsigned base2 = 0;
    if (lane == 0 && bal) base2 = atomicAdd(&s_scnt, (unsigned)__popcll(bal));
    base2 = __shfl(base2, 0);
    if (sel) {
      unsigned p = base2 + (unsigned)__popcll(bal & ((1ull << lane) - 1ull));
      if (p < SSORT)
        u.sortkeys[p] = ((unsigned long long)c << 32) |
                        (unsigned long long)(0xFFFFFFFFu - (unsigned)i);
    }
  }
  __syncthreads();
  unsigned scnt = s_scnt; if (scnt > SSORT) scnt = SSORT;
  unsigned snp = (scnt + 1u) & ~1u;
  if (tid == 0 && (scnt & 1u)) u.sortkeys[scnt] = 0ull;  // pad for b128
  __syncthreads();

  // ---- P3: rank-by-count (b128 broadcast reads) + scatter to global ----
  for (unsigned e = tid; e < scnt; e += 1024) {
    unsigned long long mykey = u.sortkeys[e];
    unsigned r = 0;
    #pragma unroll 4
    for (unsigned j = 0; j < snp; j += 2) {
      ulonglong2 kk = *reinterpret_cast<const ulonglong2*>(&u.sortkeys[j]);
      r += (kk.x > mykey) ? 1u : 0u;
      r += (kk.y > mykey) ? 1u : 0u;
    }
    if (r < 1024) {                             // == lax.top_k truncation
      unsigned a = 0xFFFFFFFFu - (unsigned)(mykey & 0xFFFFFFFFull);
      float4 cb = boxes[(size_t)b * NA_TOT + a];
      float cls = clsf[(size_t)b * NA_TOT + a];
      float* rd = g_rowd + ((size_t)b * 1024 + r) * 8;
      rd[0] = cb.x; rd[1] = cb.y; rd[2] = cb.z; rd[3] = cb.w;
      rd[4] = __uint_as_float((unsigned)(mykey >> 32));
      rd[5] = cls;
      atomicOr(&u.alive[r >> 6], 1ull << (r & 63));
      atomicAdd(&u.clsCnt[(int)cls], 1u);
    }
  }
  __syncthreads();

  if (tid < 16)   g_alive[b * 16 + tid] = u.alive[tid];
  if (tid < NCLS) g_clsc[b * NCLS + tid] = u.clsCnt[tid];
}

// ---------------------------------------------------------------------------
// Kernel 3: per-image NMS: suppression-bit rows (XOR-swizzled banks) +
// single-wave greedy walk. Exact reference-scan semantics.
// ---------------------------------------------------------------------------
struct K3Lds {
  unsigned long long rows[1024][16];    // 131072 B, col-swizzled: phys = w^(r&15)
  float    rowdata[1024][6];            //  24576 B
  unsigned list[1024];                  //   4096 B
  unsigned clsCnt[NCLS];
  unsigned clsBase[NCLS];
  unsigned clsCur[NCLS];
  unsigned long long alive[16];
};                                      // ~160.9 KB

__global__ __launch_bounds__(1024) void yolo_nms_kernel(
    const float* __restrict__ g_rowd, const unsigned long long* __restrict__ g_alive,
    const unsigned* __restrict__ g_clsc, float* __restrict__ out) {
  __shared__ K3Lds u;
  __shared__ unsigned s_efinal;
  int b    = blockIdx.x;
  int tid  = threadIdx.x;
  int lane = tid & 63;

  // ---- load rowdata / alive / clsCnt; zero rows (linear = conflict-free) ----
  {
    const float4* gr = (const float4*)(g_rowd + ((size_t)b * 1024 + tid) * 8);
    float4 v0 = gr[0];
    float4 v1 = gr[1];
    u.rowdata[tid][0] = v0.x; u.rowdata[tid][1] = v0.y;
    u.rowdata[tid][2] = v0.z; u.rowdata[tid][3] = v0.w;
    u.rowdata[tid][4] = v1.x; u.rowdata[tid][5] = v1.y;
  }
  if (tid < 16)   u.alive[tid]  = g_alive[b * 16 + tid];
  if (tid < NCLS) u.clsCnt[tid] = g_clsc[b * NCLS + tid];
  {
    unsigned long long* flat = &u.rows[0][0];
    for (int k = tid; k < 1024 * 16; k += 1024) flat[k] = 0ull;
  }
  if (tid == 0) s_efinal = 0;
  __syncthreads();

  if (tid == 0) {
    unsigned acc = 0;
    for (int c2 = 0; c2 < NCLS; ++c2) {
      u.clsBase[c2] = acc; u.clsCur[c2] = acc; acc += u.clsCnt[c2];
    }
  }
  __syncthreads();

  // ---- per-class candidate lists ----
  bool valid = (u.alive[tid >> 6] >> (tid & 63)) & 1ull;
  float mycls = u.rowdata[tid][5];
  if (valid) {
    unsigned p = atomicAdd(&u.clsCur[(int)mycls], 1u);
    u.list[p] = (unsigned)tid;
  }
  __syncthreads();

  // ---- suppression-bit rows (same-class pairs; swizzled column writes) ----
  if (valid) {
    float bx0 = u.rowdata[tid][0], by0 = u.rowdata[tid][1];
    float bw0 = u.rowdata[tid][2], bh0 = u.rowdata[tid][3];
    int c = (int)mycls;
    unsigned base = u.clsBase[c], cnt = u.clsCnt[c];
    float off = __fmul_rn(mycls, 7680.0f);
    float hw  = __fmul_rn(bw0, 0.5f), hh = __fmul_rn(bh0, 0.5f);
    float wx1 = __fadd_rn(__fsub_rn(bx0, hw), off);
    float wy1 = __fadd_rn(__fsub_rn(by0, hh), off);
    float wx2 = __fadd_rn(__fadd_rn(bx0, hw), off);
    float wy2 = __fadd_rn(__fadd_rn(by0, hh), off);
    float a1  = __fmul_rn(__fsub_rn(wx2, wx1), __fsub_rn(wy2, wy1));
    int sw = tid & 15;
    for (unsigned l = 0; l < cnt; ++l) {
      int j = (int)u.list[base + l];
      float jx = u.rowdata[j][0], jy = u.rowdata[j][1];
      float jw = u.rowdata[j][2], jh = u.rowdata[j][3];
      float jhw = __fmul_rn(jw, 0.5f), jhh = __fmul_rn(jh, 0.5f);
      float jx1 = __fadd_rn(__fsub_rn(jx, jhw), off);
      float jy1 = __fadd_rn(__fsub_rn(jy, jhh), off);
      float jx2 = __fadd_rn(__fadd_rn(jx, jhw), off);
      float jy2 = __fadd_rn(__fadd_rn(jy, jhh), off);
      float ltx = fmaxf(wx1, jx1), lty = fmaxf(wy1, jy1);
      float rbx = fminf(wx2, jx2), rby = fminf(wy2, jy2);
      float iw = fmaxf(__fsub_rn(rbx, ltx), 0.0f);
      float ih = fmaxf(__fsub_rn(rby, lty), 0.0f);
      float inter = __fmul_rn(iw, ih);
      float a2 = __fmul_rn(__fsub_rn(jx2, jx1), __fsub_rn(jy2, jy1));
      float den = __fadd_rn(__fsub_rn(__fadd_rn(a1, a2), inter), 1e-7f);
      float iou = inter / den;
      if (iou > 0.7f)
        u.rows[tid][(j >> 6) ^ sw] |= (1ull << (j & 63));
    }
  }
  __syncthreads();

  // ---- single-wave greedy walk ----
  float* orow = out + (size_t)b * (MAXDET * 6);
  if (tid < 64) {
    unsigned long long am = (lane < 16) ? u.alive[lane] : 0ull;
    int e = 0;
    while (e < MAXDET) {
      unsigned long long bal = __ballot(am != 0ull);
      if (bal == 0ull) break;
      int f    = __ffsll((unsigned long long)bal) - 1;
      int myb  = __ffsll((unsigned long long)am) - 1;
      int bitp = __shfl(myb, f);
      int r    = f * 64 + bitp;                 // winner rank (uniform)
      if (lane < 6) orow[e * 6 + lane] = u.rowdata[r][lane];
      unsigned long long rowv =
          (lane < 16) ? u.rows[r][lane ^ (r & 15)] : 0ull;  // de-swizzle
      am &= ~rowv;      // winner self-suppresses via own row bit, as reference
      ++e;
    }
    if (tid == 0) s_efinal = (unsigned)e;
  }
  __syncthreads();

  // ---- zero-fill remaining output rows ----
  for (int i = (int)s_efinal * 6 + tid; i < MAXDET * 6; i += 1024)
    orow[i] = 0.0f;
}

extern "C" void kernel_launch(void* const* d_in, const int* in_sizes, int n_in,
                              void* d_out, int out_size, void* d_ws, size_t ws_size,
                              hipStream_t stream) {
  const float* f0 = (const float*)d_in[0];
  const float* f1 = (const float*)d_in[1];
  const float* f2 = (const float*)d_in[2];
  float* out = (float*)d_out;

  char* ws = (char*)d_ws;
  float4* boxes = (float4*)ws;                                       // 4,300,800
  float*  conf  = (float*)(ws + (size_t)NBATCH * NA_TOT * 16);       // 1,075,200
  float*  clsf  = (float*)(ws + (size_t)NBATCH * NA_TOT * 20);       // 1,075,200
  float*  rowd  = (float*)(ws + (size_t)NBATCH * NA_TOT * 24);       // 1,048,576
  unsigned long long* aliv =
      (unsigned long long*)(ws + (size_t)NBATCH * NA_TOT * 24 + 1048576);  // 4 KB
  unsigned* clsc =
      (unsigned*)(ws + (size_t)NBATCH * NA_TOT * 24 + 1048576 + 4096);     // 10 KB

  yolo_decode_kernel<<<NBATCH * TILES_PER_IMG, 256, 0, stream>>>(
      f0, f1, f2, boxes, conf, clsf);
  yolo_select_kernel<<<NBATCH, 1024, 0, stream>>>(boxes, conf, clsf,
                                                  rowd, aliv, clsc);
  yolo_nms_kernel<<<NBATCH, 1024, 0, stream>>>(rowd, aliv, clsc, out);
}

// Round 6
// 159.792 us; speedup vs baseline: 1.3712x; 1.0171x over previous
//
#include <hip/hip_runtime.h>
#include <stdint.h>

#define NCLS    80
#define NA_TOT  8400     // 6400 + 1600 + 400
#define NBATCH  32
#define MAXDET  300
#define SSORT   2048
#define RANKCAP 1536
#define CONFTHR 0.001f
#define BLKS_PER_IMG 34   // 25 + 7 + 2 blocks of 256 anchors

// ---------------------------------------------------------------------------
// Bit-exact reconstruction of XLA:CPU f32 exp (Eigen/Cephes pexp, no FMA) and
// logistic = 1/(1+exp(-x)). Validated absmax==0.0 rounds 1-5. DO NOT TOUCH.
// ---------------------------------------------------------------------------
__device__ __forceinline__ float xla_expf(float in) {
  const float exp_hi = 88.3762626647950f;
  const float exp_lo = -88.3762626647949f;
  const float LOG2EF = 1.44269504088896341f;
  const float C1 = 0.693359375f;
  const float C2 = -2.12194440e-4f;
  const float p0 = 1.9875691500E-4f, p1 = 1.3981999507E-3f, p2 = 8.3334519073E-3f;
  const float p3 = 4.1665795894E-2f, p4 = 1.6666665459E-1f, p5 = 5.0000001201E-1f;
  float x = fminf(fmaxf(in, exp_lo), exp_hi);
  float fx = floorf(__fadd_rn(__fmul_rn(x, LOG2EF), 0.5f));
  float tmp = __fmul_rn(C1, fx);
  float z   = __fmul_rn(C2, fx);
  x = __fsub_rn(x, tmp);
  x = __fsub_rn(x, z);
  float y = __fadd_rn(__fmul_rn(x, p0), p1);
  y = __fadd_rn(__fmul_rn(y, x), p2);
  y = __fadd_rn(__fmul_rn(y, x), p3);
  y = __fadd_rn(__fmul_rn(y, x), p4);
  y = __fadd_rn(__fmul_rn(y, x), p5);
  y = __fadd_rn(__fmul_rn(y, __fmul_rn(x, x)), x);
  y = __fadd_rn(1.0f, y);
  int m = (int)fx;
  float s = __uint_as_float((uint32_t)(m + 127) << 23);
  float r = __fmul_rn(y, s);
  return fmaxf(r, in);
}

__device__ __forceinline__ float xla_sigmoid(float v) {
  float e = xla_expf(-v);
  float den = __fadd_rn(1.0f, e);
  return 1.0f / den;
}

// ---------------------------------------------------------------------------
// Kernel 1: register-direct decode. One thread = one anchor; every channel
// load is wave-coalesced (consecutive anchors). All 64 DFL channels + a
// 32-class batch issued up front for MLP; no LDS, no barrier.
// Per-anchor FP sequences bit-identical to validated r1.
// ---------------------------------------------------------------------------
__global__ __launch_bounds__(256) void yolo_decode_kernel(
    const float* __restrict__ f0, const float* __restrict__ f1,
    const float* __restrict__ f2,
    float4* __restrict__ oboxes, float* __restrict__ oconf,
    float* __restrict__ oclsf) {
  int bx  = blockIdx.x;
  int b   = bx / BLKS_PER_IMG;
  int r   = bx - b * BLKS_PER_IMG;
  int tid = threadIdx.x;

  const float* base; int a0, W, NV, aG0; float stridef;
  if (r < 25)      { base = f0 + (size_t)b * (144 * 6400); W = 80; a0 = r * 256;
                     NV = 256; stridef = 8.0f;  aG0 = a0; }
  else if (r < 32) { base = f1 + (size_t)b * (144 * 1600); W = 40; a0 = (r - 25) * 256;
                     NV = (a0 + 256 <= 1600) ? 256 : (1600 - a0);
                     stridef = 16.0f; aG0 = 6400 + a0; }
  else             { base = f2 + (size_t)b * (144 * 400);  W = 20; a0 = (r - 32) * 256;
                     NV = (a0 + 256 <= 400) ? 256 : (400 - a0);
                     stridef = 32.0f; aG0 = 8000 + a0; }
  if (tid >= NV) return;
  int Alvl = W * W;
  int ai = a0 + tid;
  const float* cp = base + ai;

  // ---- issue all 64 DFL loads + first 32 class loads (all coalesced) ----
  float d[64];
  #pragma unroll
  for (int ch = 0; ch < 64; ++ch) d[ch] = cp[(size_t)ch * Alvl];
  float cv[32];
  #pragma unroll
  for (int k = 0; k < 32; ++k) cv[k] = cp[(size_t)(64 + k) * Alvl];

  float ax = __fadd_rn((float)(ai % W), 0.5f);
  float ay = __fadd_rn((float)(ai / W), 0.5f);

  // ---- DFL softmax-expectation (bit-exact r1 sequence) ----
  float ltrb[4];
  #pragma unroll
  for (int fs = 0; fs < 4; ++fs) {
    float mx = -INFINITY;
    #pragma unroll
    for (int rr = 0; rr < 16; ++rr) mx = fmaxf(mx, d[fs * 16 + rr]);
    float e[16]; float ssum = 0.0f;
    #pragma unroll
    for (int rr = 0; rr < 16; ++rr) {
      e[rr] = xla_expf(__fsub_rn(d[fs * 16 + rr], mx));
      ssum = __fadd_rn(ssum, e[rr]);
    }
    float acc = 0.0f;
    #pragma unroll
    for (int rr = 0; rr < 16; ++rr) {
      float p = e[rr] / ssum;
      acc = __fadd_rn(acc, __fmul_rn(p, (float)rr));
    }
    ltrb[fs] = acc;
  }

  float x1 = __fsub_rn(ax, ltrb[0]);
  float y1 = __fsub_rn(ay, ltrb[1]);
  float x2 = __fadd_rn(ax, ltrb[2]);
  float y2 = __fadd_rn(ay, ltrb[3]);
  float cx = __fmul_rn(__fadd_rn(x1, x2), 0.5f);
  float cy = __fmul_rn(__fadd_rn(y1, y2), 0.5f);
  float w  = __fsub_rn(x2, x1);
  float h  = __fsub_rn(y2, y1);
  float4 box = make_float4(__fmul_rn(cx, stridef), __fmul_rn(cy, stridef),
                           __fmul_rn(w, stridef),  __fmul_rn(h, stridef));

  // ---- class top-2 scan, ascending k, strict > (== r1 semantics) ----
  float best = -INFINITY, second = -INFINITY; int bi = 0;
  #pragma unroll
  for (int k = 0; k < 32; ++k) {
    float v = cv[k];
    if (v > best)        { second = best; best = v; bi = k; }
    else if (v > second) { second = v; }
  }
  #pragma unroll
  for (int k = 0; k < 32; ++k) cv[k] = cp[(size_t)(96 + k) * Alvl];
  #pragma unroll
  for (int k = 0; k < 32; ++k) {
    float v = cv[k];
    if (v > best)        { second = best; best = v; bi = 32 + k; }
    else if (v > second) { second = v; }
  }
  #pragma unroll
  for (int k = 0; k < 16; ++k) cv[k] = cp[(size_t)(128 + k) * Alvl];
  #pragma unroll
  for (int k = 0; k < 16; ++k) {
    float v = cv[k];
    if (v > best)        { second = best; best = v; bi = 64 + k; }
    else if (v > second) { second = v; }
  }

  float conf; int cls = bi;
  if (__fsub_rn(best, second) < 1e-4f || best > 5.0f) {
    // exact slow path (rare): identical to validated r1 80-sigmoid scan
    float bs = -INFINITY; int bj = 0;
    for (int k = 0; k < NCLS; ++k) {
      float v = cp[(size_t)(64 + k) * Alvl];
      float s = xla_sigmoid(v);
      if (s > bs) { bs = s; bj = k; }
    }
    conf = bs; cls = bj;
  } else {
    conf = xla_sigmoid(best);
  }

  int t = b * NA_TOT + aG0 + tid;
  oboxes[t] = box;
  conf = (conf > CONFTHR) ? conf : 0.0f;
  oconf[t] = conf;
  oclsf[t] = (float)cls;
}

// ---------------------------------------------------------------------------
// Kernel 2: per-image exact top-1024 select + rank (validated r5, unchanged).
// ---------------------------------------------------------------------------
struct __align__(16) K2Lds {
  unsigned long long sortkeys[SSORT];   // 16384 B (offset 0: 16B-aligned)
  unsigned confL[NA_TOT];               // 33600 B
  unsigned hist[16][257];               // 16448 B (per-wave, padded)
  unsigned tot[257];
  unsigned Tarr[257];
  unsigned long long alive[16];
  unsigned clsCnt[NCLS];
};                                      // ~69 KB

__global__ __launch_bounds__(1024) void yolo_select_kernel(
    const float4* __restrict__ boxes, const float* __restrict__ conf,
    const float* __restrict__ clsf,
    float* __restrict__ g_rowd, unsigned long long* __restrict__ g_alive,
    unsigned* __restrict__ g_clsc) {
  __shared__ K2Lds u;
  __shared__ unsigned s_need, s_prefix, s_found, s_B, s_scnt, s_cut, s_done;
  int b    = blockIdx.x;
  int tid  = threadIdx.x;
  int lane = tid & 63;
  int wv   = tid >> 6;
  const unsigned* confu = (const unsigned*)conf + (size_t)b * NA_TOT;

  // ---- P0: stage conf bits; zero outputs ----
  for (int i = tid; i < NA_TOT; i += 1024) u.confL[i] = confu[i];
  {
    float4 z4 = make_float4(0.f, 0.f, 0.f, 0.f);
    float4* gr = (float4*)(g_rowd + (size_t)b * 1024 * 8);
    for (int k = tid; k < 2048; k += 1024) gr[k] = z4;   // 1024 rows x 32 B
  }
  if (tid < NCLS) u.clsCnt[tid] = 0;
  if (tid < 16)   u.alive[tid]  = 0ull;
  if (tid == 0) { s_need = 1024; s_prefix = 0; s_cut = 0; s_done = 0; s_scnt = 0; }
  __syncthreads();

  // ---- P1: adaptive 8-bit radix descent (exact selcnt bound) ----
  for (int lv = 0; lv < 4; ++lv) {
    __syncthreads();
    if (s_done) break;                          // uniform
    for (int i = tid; i < 16 * 257; i += 1024) ((unsigned*)u.hist)[i] = 0;
    if (tid == 0) { s_found = 0; s_B = 0; }
    __syncthreads();
    unsigned pfx = s_prefix;
    for (int it = 0; it < 9; ++it) {
      int i = tid + it * 1024;
      unsigned c = (i < NA_TOT) ? u.confL[i] : 0u;
      bool in; unsigned bin;
      if (lv == 0)      { in = true;                bin = c >> 23; }
      else if (lv == 1) { in = ((c >> 23) == pfx);  bin = (c >> 15) & 0xFF; }
      else if (lv == 2) { in = ((c >> 15) == pfx);  bin = (c >> 7) & 0xFF; }
      else              { in = ((c >> 7)  == pfx);  bin = c & 0x7F; }
      bool act = (c != 0) && in;
      unsigned long long ab = __ballot(act);
      if (ab) {                                 // wave-uniform branch
        int fl = __ffsll(ab) - 1;
        unsigned fbin = __shfl(bin, fl);
        unsigned long long same = __ballot(act && (bin == fbin));
        if (same == ab) {                       // all active lanes same bin
          if (lane == fl) atomicAdd(&u.hist[wv][fbin], (unsigned)__popcll(ab));
        } else if (act) {
          atomicAdd(&u.hist[wv][bin], 1u);
        }
      }
    }
    __syncthreads();
    if (tid < 256) {                            // reduce 16 wave-hists
      unsigned s = 0;
      #pragma unroll
      for (int q = 0; q < 16; ++q) s += u.hist[q][tid];
      u.tot[tid] = s;
    }
    __syncthreads();
    if (tid < 64) {                             // suffix scan (4 chunks of 64)
      unsigned carry = 0;
      if (tid == 0) u.Tarr[256] = 0;
      for (int ch = 3; ch >= 0; --ch) {
        int bb = ch * 64 + tid;
        unsigned v = u.tot[bb];
        #pragma unroll
        for (int off = 1; off < 64; off <<= 1) {
          unsigned t2 = __shfl_down(v, off);
          if (tid + off < 64) v += t2;
        }
        u.Tarr[bb] = v + carry;
        carry += __shfl(v, 0);
      }
    }
    __syncthreads();
    unsigned need = s_need;
    if (tid < 256) {
      unsigned h = u.tot[tid];
      if (h > 0 && u.Tarr[tid + 1] < need && u.Tarr[tid + 1] + h >= need) {
        s_B = (unsigned)tid; s_found = 1;       // unique writer (T monotone)
      }
    }
    __syncthreads();
    if (tid == 0) {
      if (!s_found) { s_cut = 1; s_done = 1; }  // <1024 nonzero total (lv0)
      else {
        unsigned B = s_B;
        unsigned selcnt = (1024u - need) + u.Tarr[B];  // exact: committed + >=binB
        if (selcnt <= (unsigned)RANKCAP || lv == 3) {
          s_done = 1;
          if (lv == 0)      s_cut = B << 23;
          else if (lv == 1) s_cut = (s_prefix << 23) | (B << 15);
          else if (lv == 2) s_cut = (s_prefix << 15) | (B << 7);
          else              s_cut = (s_prefix << 7)  | B;
        } else {
          s_need   = need - u.Tarr[B + 1];
          s_prefix = (s_prefix << 8) | B;
        }
      }
    }
  }
  __syncthreads();

  // ---- P2: ballot-aggregated compact ----
  unsigned cut = s_cut;
  for (int it = 0; it < 9; ++it) {
    int i = tid + it * 1024;
    unsigned c = (i < NA_TOT) ? u.confL[i] : 0u;
    bool sel = (c != 0 && c >= cut);
    unsigned long long bal = __ballot(sel);
    unsigned base2 = 0;
    if (lane == 0 && bal) base2 = atomicAdd(&s_scnt, (unsigned)__popcll(bal));
    base2 = __shfl(base2, 0);
    if (sel) {
      unsigned p = base2 + (unsigned)__popcll(bal & ((1ull << lane) - 1ull));
      if (p < SSORT)
        u.sortkeys[p] = ((unsigned long long)c << 32) |
                        (unsigned long long)(0xFFFFFFFFu - (unsigned)i);
    }
  }
  __syncthreads();
  unsigned scnt = s_scnt; if (scnt > SSORT) scnt = SSORT;
  unsigned snp = (scnt + 1u) & ~1u;
  if (tid == 0 && (scnt & 1u)) u.sortkeys[scnt] = 0ull;  // pad for b128
  __syncthreads();

  // ---- P3: rank-by-count (b128 broadcast reads) + scatter to global ----
  for (unsigned e = tid; e < scnt; e += 1024) {
    unsigned long long mykey = u.sortkeys[e];
    unsigned r = 0;
    #pragma unroll 4
    for (unsigned j = 0; j < snp; j += 2) {
      ulonglong2 kk = *reinterpret_cast<const ulonglong2*>(&u.sortkeys[j]);
      r += (kk.x > mykey) ? 1u : 0u;
      r += (kk.y > mykey) ? 1u : 0u;
    }
    if (r < 1024) {                             // == lax.top_k truncation
      unsigned a = 0xFFFFFFFFu - (unsigned)(mykey & 0xFFFFFFFFull);
      float4 cb = boxes[(size_t)b * NA_TOT + a];
      float cls = clsf[(size_t)b * NA_TOT + a];
      float* rd = g_rowd + ((size_t)b * 1024 + r) * 8;
      rd[0] = cb.x; rd[1] = cb.y; rd[2] = cb.z; rd[3] = cb.w;
      rd[4] = __uint_as_float((unsigned)(mykey >> 32));
      rd[5] = cls;
      atomicOr(&u.alive[r >> 6], 1ull << (r & 63));
      atomicAdd(&u.clsCnt[(int)cls], 1u);
    }
  }
  __syncthreads();

  if (tid < 16)   g_alive[b * 16 + tid] = u.alive[tid];
  if (tid < NCLS) g_clsc[b * NCLS + tid] = u.clsCnt[tid];
}

// ---------------------------------------------------------------------------
// Kernel 3: per-image NMS (validated r5, unchanged): swizzled suppression-bit
// rows + single-wave greedy walk. Exact reference-scan semantics.
// ---------------------------------------------------------------------------
struct K3Lds {
  unsigned long long rows[1024][16];    // 131072 B, col-swizzled: phys = w^(r&15)
  float    rowdata[1024][6];            //  24576 B
  unsigned list[1024];                  //   4096 B
  unsigned clsCnt[NCLS];
  unsigned clsBase[NCLS];
  unsigned clsCur[NCLS];
  unsigned long long alive[16];
};                                      // ~160.9 KB

__global__ __launch_bounds__(1024) void yolo_nms_kernel(
    const float* __restrict__ g_rowd, const unsigned long long* __restrict__ g_alive,
    const unsigned* __restrict__ g_clsc, float* __restrict__ out) {
  __shared__ K3Lds u;
  __shared__ unsigned s_efinal;
  int b    = blockIdx.x;
  int tid  = threadIdx.x;
  int lane = tid & 63;

  // ---- load rowdata / alive / clsCnt; zero rows (linear = conflict-free) ----
  {
    const float4* gr = (const float4*)(g_rowd + ((size_t)b * 1024 + tid) * 8);
    float4 v0 = gr[0];
    float4 v1 = gr[1];
    u.rowdata[tid][0] = v0.x; u.rowdata[tid][1] = v0.y;
    u.rowdata[tid][2] = v0.z; u.rowdata[tid][3] = v0.w;
    u.rowdata[tid][4] = v1.x; u.rowdata[tid][5] = v1.y;
  }
  if (tid < 16)   u.alive[tid]  = g_alive[b * 16 + tid];
  if (tid < NCLS) u.clsCnt[tid] = g_clsc[b * NCLS + tid];
  {
    unsigned long long* flat = &u.rows[0][0];
    for (int k = tid; k < 1024 * 16; k += 1024) flat[k] = 0ull;
  }
  if (tid == 0) s_efinal = 0;
  __syncthreads();

  if (tid == 0) {
    unsigned acc = 0;
    for (int c2 = 0; c2 < NCLS; ++c2) {
      u.clsBase[c2] = acc; u.clsCur[c2] = acc; acc += u.clsCnt[c2];
    }
  }
  __syncthreads();

  // ---- per-class candidate lists ----
  bool valid = (u.alive[tid >> 6] >> (tid & 63)) & 1ull;
  float mycls = u.rowdata[tid][5];
  if (valid) {
    unsigned p = atomicAdd(&u.clsCur[(int)mycls], 1u);
    u.list[p] = (unsigned)tid;
  }
  __syncthreads();

  // ---- suppression-bit rows (same-class pairs; swizzled column writes) ----
  if (valid) {
    float bx0 = u.rowdata[tid][0], by0 = u.rowdata[tid][1];
    float bw0 = u.rowdata[tid][2], bh0 = u.rowdata[tid][3];
    int c = (int)mycls;
    unsigned base = u.clsBase[c], cnt = u.clsCnt[c];
    float off = __fmul_rn(mycls, 7680.0f);
    float hw  = __fmul_rn(bw0, 0.5f), hh = __fmul_rn(bh0, 0.5f);
    float wx1 = __fadd_rn(__fsub_rn(bx0, hw), off);
    float wy1 = __fadd_rn(__fsub_rn(by0, hh), off);
    float wx2 = __fadd_rn(__fadd_rn(bx0, hw), off);
    float wy2 = __fadd_rn(__fadd_rn(by0, hh), off);
    float a1  = __fmul_rn(__fsub_rn(wx2, wx1), __fsub_rn(wy2, wy1));
    int sw = tid & 15;
    for (unsigned l = 0; l < cnt; ++l) {
      int j = (int)u.list[base + l];
      float jx = u.rowdata[j][0], jy = u.rowdata[j][1];
      float jw = u.rowdata[j][2], jh = u.rowdata[j][3];
      float jhw = __fmul_rn(jw, 0.5f), jhh = __fmul_rn(jh, 0.5f);
      float jx1 = __fadd_rn(__fsub_rn(jx, jhw), off);
      float jy1 = __fadd_rn(__fsub_rn(jy, jhh), off);
      float jx2 = __fadd_rn(__fadd_rn(jx, jhw), off);
      float jy2 = __fadd_rn(__fadd_rn(jy, jhh), off);
      float ltx = fmaxf(wx1, jx1), lty = fmaxf(wy1, jy1);
      float rbx = fminf(wx2, jx2), rby = fminf(wy2, jy2);
      float iw = fmaxf(__fsub_rn(rbx, ltx), 0.0f);
      float ih = fmaxf(__fsub_rn(rby, lty), 0.0f);
      float inter = __fmul_rn(iw, ih);
      float a2 = __fmul_rn(__fsub_rn(jx2, jx1), __fsub_rn(jy2, jy1));
      float den = __fadd_rn(__fsub_rn(__fadd_rn(a1, a2), inter), 1e-7f);
      float iou = inter / den;
      if (iou > 0.7f)
        u.rows[tid][(j >> 6) ^ sw] |= (1ull << (j & 63));
    }
  }
  __syncthreads();

  // ---- single-wave greedy walk ----
  float* orow = out + (size_t)b * (MAXDET * 6);
  if (tid < 64) {
    unsigned long long am = (lane < 16) ? u.alive[lane] : 0ull;
    int e = 0;
    while (e < MAXDET) {
      unsigned long long bal = __ballot(am != 0ull);
      if (bal == 0ull) break;
      int f    = __ffsll((unsigned long long)bal) - 1;
      int myb  = __ffsll((unsigned long long)am) - 1;
      int bitp = __shfl(myb, f);
      int r    = f * 64 + bitp;                 // winner rank (uniform)
      if (lane < 6) orow[e * 6 + lane] = u.rowdata[r][lane];
      unsigned long long rowv =
          (lane < 16) ? u.rows[r][lane ^ (r & 15)] : 0ull;  // de-swizzle
      am &= ~rowv;      // winner self-suppresses via own row bit, as reference
      ++e;
    }
    if (tid == 0) s_efinal = (unsigned)e;
  }
  __syncthreads();

  // ---- zero-fill remaining output rows ----
  for (int i = (int)s_efinal * 6 + tid; i < MAXDET * 6; i += 1024)
    orow[i] = 0.0f;
}

extern "C" void kernel_launch(void* const* d_in, const int* in_sizes, int n_in,
                              void* d_out, int out_size, void* d_ws, size_t ws_size,
                              hipStream_t stream) {
  const float* f0 = (const float*)d_in[0];
  const float* f1 = (const float*)d_in[1];
  const float* f2 = (const float*)d_in[2];
  float* out = (float*)d_out;

  char* ws = (char*)d_ws;
  float4* boxes = (float4*)ws;                                       // 4,300,800
  float*  conf  = (float*)(ws + (size_t)NBATCH * NA_TOT * 16);       // 1,075,200
  float*  clsf  = (float*)(ws + (size_t)NBATCH * NA_TOT * 20);       // 1,075,200
  float*  rowd  = (float*)(ws + (size_t)NBATCH * NA_TOT * 24);       // 1,048,576
  unsigned long long* aliv =
      (unsigned long long*)(ws + (size_t)NBATCH * NA_TOT * 24 + 1048576);  // 4 KB
  unsigned* clsc =
      (unsigned*)(ws + (size_t)NBATCH * NA_TOT * 24 + 1048576 + 4096);     // 10 KB

  yolo_decode_kernel<<<NBATCH * BLKS_PER_IMG, 256, 0, stream>>>(
      f0, f1, f2, boxes, conf, clsf);
  yolo_select_kernel<<<NBATCH, 1024, 0, stream>>>(boxes, conf, clsf,
                                                  rowd, aliv, clsc);
  yolo_nms_kernel<<<NBATCH, 1024, 0, stream>>>(rowd, aliv, clsc, out);
}